// Round 7
// baseline (21.466 us; speedup 1.0000x reference)
//
#include <hip/hip_runtime.h>

// B=131072, S=4, D=128, H=1
//   u[b] = dot(x[b,0,:], w) + bias     (reads only first S-slice: 64 MB)
//   y[b] = u[b] + a*y[b-1],  a = weight_h[0,0]
// K1: streaming dot, GRID-STRIDED row mapping (live set = contiguous 32MB
//     sweep -> DRAM page locality), 8 loads hoisted (deep MLP), 32 waves/CU.
// K2: fused scan + decoupled lookback + write (512 blocks).

#define B_ROWS 131072
#define CHUNK  256
#define NCHUNK 512   // B_ROWS / CHUNK
#define MAGIC  0x7C3A9E51u

template <int CTRL>
__device__ __forceinline__ float dpp_add(float s) {
    int v = __builtin_amdgcn_update_dpp(0, __builtin_bit_cast(int, s), CTRL, 0xF, 0xF, true);
    return s + __builtin_bit_cast(float, v);
}

// ---- K1: per-row dot. Half-wave per row; iteration r covers rows
// [r*16384, r*16384+16384) across the whole grid (contiguous sweep). ----
__global__ __launch_bounds__(256) void k_dot(const float* __restrict__ x,
                                             const float* __restrict__ w,
                                             const float* __restrict__ bias,
                                             float* __restrict__ u) {
    const int gtid = blockIdx.x * 256 + threadIdx.x;
    const int wave = gtid >> 6;        // 0..8191
    const int lane = threadIdx.x & 63;
    const int half = lane >> 5;        // which row of the pair
    const int hl   = lane & 31;        // lane within half-wave
    const float4 wv = *reinterpret_cast<const float4*>(w + hl * 4);
    const float  bs = bias[0];
    const int rbase = wave * 2 + half; // this thread's row at iteration 0

    // Hoist all 8 loads: 8 KB per wave in flight before any reduce.
    float4 xv[8];
#pragma unroll
    for (int r = 0; r < 8; ++r) {
        const int row = rbase + r * 16384;
        xv[r] = *reinterpret_cast<const float4*>(x + (size_t)row * 512 + hl * 4);
    }
#pragma unroll
    for (int r = 0; r < 8; ++r) {
        float s = fmaf(xv[r].x, wv.x, fmaf(xv[r].y, wv.y,
                  fmaf(xv[r].z, wv.z, xv[r].w * wv.w)));
        s = dpp_add<0xB1>(s);    // xor1 (quad_perm)
        s = dpp_add<0x4E>(s);    // xor2 (quad_perm)
        s = dpp_add<0x141>(s);   // row_half_mirror
        s = dpp_add<0x140>(s);   // row_mirror
        s += __shfl_xor(s, 16, 64);
        if (hl == 0) u[rbase + r * 16384] = s + bs;
    }
}

// ---- K2: block scan of u + decoupled lookback + direct output write. ----
__global__ __launch_bounds__(256) void k_scan_apply(const float* __restrict__ u,
                                                    const float* __restrict__ wh_p,
                                                    unsigned long long* __restrict__ pk,
                                                    float* __restrict__ out) {
    __shared__ float wl[4];
    __shared__ float Sw[8];
    __shared__ float ex_s;
    const int tid  = threadIdx.x;
    const int wv   = tid >> 6;
    const int lane = tid & 63;
    const int k    = blockIdx.x;
    const int base = k * CHUNK;

    // u arrives coalesced, already in scan lane order: no LDS round-trip.
    const float a = wh_p[0];
    float c = u[base + tid];
    float fstep = a;
#pragma unroll
    for (int s = 1; s < 64; s <<= 1) {
        float prev = __shfl_up(c, (unsigned)s, 64);
        if (lane >= s) c = fmaf(prev, fstep, c);
        fstep *= fstep;
    }
    const float f64 = fstep;            // a^64
    float apw = a, bse = a;             // a^(lane+1)
#pragma unroll
    for (int b = 0; b < 6; ++b) { if (lane & (1 << b)) apw *= bse; bse *= bse; }

    if (lane == 63) wl[wv] = c;
    __syncthreads();
    if (wv > 0) {
        float seed = wl[0];
#pragma unroll
        for (int j = 1; j < 4; ++j) if (j < wv) seed = fmaf(seed, f64, wl[j]);
        c = fmaf(seed, apw, c);         // block-wide inclusive prefix
    }

    // Publish chunk aggregate (value packed WITH flag: no fences needed).
    if (tid == CHUNK - 1) {
        unsigned long long q =
            ((unsigned long long)__float_as_uint(c) << 32) | (unsigned long long)MAGIC;
        __hip_atomic_store(&pk[k], q, __ATOMIC_RELAXED, __HIP_MEMORY_SCOPE_AGENT);
    }

    // Lookback: nw windows of 64 predecessors, distributed across 4 waves.
    const float Af = [&]{ float t2 = f64 * f64; return t2 * t2; }();   // a^256
    const int nw = (k + 63) >> 6;
    for (int wi = wv; wi < nw; wi += 4) {
        const int j0 = wi << 6;
        const int t  = min(64, k - j0);     // chunks in this window, 1..64
        float cj = 0.0f;
        if (lane < t) {
            unsigned long long q = __hip_atomic_load(&pk[j0 + lane], __ATOMIC_RELAXED,
                                                     __HIP_MEMORY_SCOPE_AGENT);
            while ((unsigned int)q != MAGIC) {
                __builtin_amdgcn_s_sleep(1);
                q = __hip_atomic_load(&pk[j0 + lane], __ATOMIC_RELAXED,
                                      __HIP_MEMORY_SCOPE_AGENT);
            }
            cj = __uint_as_float((unsigned int)(q >> 32));
        }
        float P = cj, ff = Af;              // weighted scan; lane t-1 = window sum
#pragma unroll
        for (int s = 1; s < 64; s <<= 1) {
            float prev = __shfl_up(P, (unsigned)s, 64);
            if (lane >= s) P = fmaf(prev, ff, P);
            ff *= ff;
        }
        if (lane == t - 1) Sw[wi] = P;
    }
    __syncthreads();

    if (tid == 0) {
        float ex = 0.0f;
        if (nw > 0) {
            float A64 = Af;
#pragma unroll
            for (int i = 0; i < 6; ++i) A64 *= A64;       // Af^64
            for (int wi = 0; wi < nw - 1; ++wi) ex = fmaf(ex, A64, Sw[wi]);
            const int tl = k - ((nw - 1) << 6);           // last-window length 1..64
            float At = 1.0f, bb = Af;
#pragma unroll
            for (int b = 0; b < 7; ++b) { if (tl & (1 << b)) At *= bb; bb *= bb; }
            ex = fmaf(ex, At, Sw[nw - 1]);
        }
        ex_s = ex;
    }
    __syncthreads();

    // y_i = p_i + a^(i+1) * ex ; direct coalesced store.
    const float ex = ex_s;
    float pw = apw;
#pragma unroll
    for (int j = 0; j < 4; ++j) if (j < wv) pw *= f64;   // -> a^(tid+1)
    const float y = fmaf(pw, ex, c);
    out[base + tid] = y;
    if (k == NCHUNK - 1 && tid == CHUNK - 1) {           // y_h duplicated tail
        out[B_ROWS]     = y;
        out[B_ROWS + 1] = y;
    }
}

extern "C" void kernel_launch(void* const* d_in, const int* in_sizes, int n_in,
                              void* d_out, int out_size, void* d_ws, size_t ws_size,
                              hipStream_t stream) {
    const float* x    = (const float*)d_in[0];   // (131072, 4, 128) f32
    const float* w    = (const float*)d_in[1];   // (128, 1) f32
    const float* wh   = (const float*)d_in[2];   // (1, 1) f32
    const float* bias = (const float*)d_in[3];   // (1,) f32
    float* out = (float*)d_out;                  // 131074 f32

    float* u               = (float*)d_ws;                      // B_ROWS floats
    unsigned long long* pk = (unsigned long long*)(u + B_ROWS); // NCHUNK qwords

    k_dot<<<2048, 256, 0, stream>>>(x, w, bias, u);
    k_scan_apply<<<NCHUNK, 256, 0, stream>>>(u, wh, pk, out);
}